// Round 1
// baseline (1024.894 us; speedup 1.0000x reference)
//
#include <hip/hip_runtime.h>

// ---------------------------------------------------------------------------
// NASNet controller: 8 sequential LSTM steps (B=4096, H=512) + 16 decisions.
// Key transforms:
//  - E = emb @ w_ih^T + b_ih + b_hh precomputed once ([9,2048]); per-step input
//    contribution is a row gather -> halves GEMM FLOPs.
//  - step 0: h=c=0 -> GEMM skipped (gates = E[token0]).
//  - GEMM tile 128 rows x (32 j x 4 gates) so the epilogue fuses the full LSTM
//    pointwise update (gates never hit HBM).
// ---------------------------------------------------------------------------

constexpr int Bsz = 4096;
constexpr int Hsz = 512;
constexpr int G4H = 2048;

// ---------------- E = emb @ w_ih^T + b_ih + b_hh ---------------------------
__global__ __launch_bounds__(256) void precompute_E(
    const float* __restrict__ emb, const float* __restrict__ w_ih,
    const float* __restrict__ b_ih, const float* __restrict__ b_hh,
    float* __restrict__ E) {
  int idx = blockIdx.x * 256 + threadIdx.x;  // t*2048 + col
  int t = idx >> 11;
  int col = idx & 2047;
  const float* er = emb + (size_t)t * Hsz;
  const float* wr = w_ih + (size_t)col * Hsz;
  float acc = 0.0f;
  for (int k = 0; k < Hsz; k += 4) {
    float4 e = *(const float4*)(er + k);
    float4 w = *(const float4*)(wr + k);
    acc += e.x * w.x + e.y * w.y + e.z * w.z + e.w * w.w;
  }
  E[idx] = acc + b_ih[col] + b_hh[col];
}

// ---------------- fused gates GEMM + LSTM pointwise ------------------------
// out cols per block: gate g in {i,f,g,o}, j in [j0, j0+32). Tile col index
// ct in [0,128): j_local = ct>>2, g = ct&3  (interleaved so each thread's 8
// consecutive cols = 2 j's x 4 gates -> epilogue has i,f,g,o locally).
__global__ __launch_bounds__(256) void lstm_gemm(
    const float* __restrict__ h_in, float* __restrict__ c_io,
    const float* __restrict__ E, const int* __restrict__ act,
    const float* __restrict__ w_hh, float* __restrict__ h_out, int step) {
  constexpr int LDT = 132;  // padded LDS stride (16B-aligned rows, no pow2)
  __shared__ float As[16 * LDT];
  __shared__ float Bs[16 * LDT];
  __shared__ float Es[9 * 128];

  const int tid = threadIdx.x;
  const int bx = blockIdx.x & 15;   // col group
  const int by = blockIdx.x >> 4;   // row group
  const int r0 = by * 128;
  const int j0 = bx * 32;
  const int tx = tid & 15;
  const int ty = tid >> 4;

  // stage the E tile this block needs: Es[t][ct]
  for (int idx = tid; idx < 9 * 128; idx += 256) {
    int t = idx >> 7;
    int ct = idx & 127;
    Es[idx] = E[(size_t)t * G4H + ((ct & 3) << 9) + j0 + (ct >> 2)];
  }

  float acc[8][8];
#pragma unroll
  for (int i = 0; i < 8; ++i)
#pragma unroll
    for (int j = 0; j < 8; ++j) acc[i][j] = 0.0f;

  if (step > 0) {
    const int lr = tid >> 2;         // 0..63
    const int lk = (tid & 3) << 2;   // 0,4,8,12
    const int ct0 = lr, ct1 = lr + 64;
    const int wrow0 = ((ct0 & 3) << 9) + j0 + (ct0 >> 2);
    const int wrow1 = ((ct1 & 3) << 9) + j0 + (ct1 >> 2);
    const float* ha = h_in + (size_t)(r0 + lr) * Hsz;
    const float* hb = h_in + (size_t)(r0 + lr + 64) * Hsz;
    const float* wa = w_hh + (size_t)wrow0 * Hsz;
    const float* wb = w_hh + (size_t)wrow1 * Hsz;

    for (int k0 = 0; k0 < Hsz; k0 += 16) {
      float4 a0 = *(const float4*)(ha + k0 + lk);
      float4 a1 = *(const float4*)(hb + k0 + lk);
      float4 b0 = *(const float4*)(wa + k0 + lk);
      float4 b1 = *(const float4*)(wb + k0 + lk);
      __syncthreads();  // prior iter's reads done before overwrite
      As[(lk + 0) * LDT + lr] = a0.x;
      As[(lk + 1) * LDT + lr] = a0.y;
      As[(lk + 2) * LDT + lr] = a0.z;
      As[(lk + 3) * LDT + lr] = a0.w;
      As[(lk + 0) * LDT + lr + 64] = a1.x;
      As[(lk + 1) * LDT + lr + 64] = a1.y;
      As[(lk + 2) * LDT + lr + 64] = a1.z;
      As[(lk + 3) * LDT + lr + 64] = a1.w;
      Bs[(lk + 0) * LDT + lr] = b0.x;
      Bs[(lk + 1) * LDT + lr] = b0.y;
      Bs[(lk + 2) * LDT + lr] = b0.z;
      Bs[(lk + 3) * LDT + lr] = b0.w;
      Bs[(lk + 0) * LDT + lr + 64] = b1.x;
      Bs[(lk + 1) * LDT + lr + 64] = b1.y;
      Bs[(lk + 2) * LDT + lr + 64] = b1.z;
      Bs[(lk + 3) * LDT + lr + 64] = b1.w;
      __syncthreads();
#pragma unroll
      for (int kk = 0; kk < 16; ++kk) {
        const float* Ab = &As[kk * LDT + (ty << 3)];
        const float* Bb = &Bs[kk * LDT + (tx << 3)];
        float4 av0 = *(const float4*)(Ab);
        float4 av1 = *(const float4*)(Ab + 4);
        float4 bv0 = *(const float4*)(Bb);
        float4 bv1 = *(const float4*)(Bb + 4);
        float av[8] = {av0.x, av0.y, av0.z, av0.w, av1.x, av1.y, av1.z, av1.w};
        float bv[8] = {bv0.x, bv0.y, bv0.z, bv0.w, bv1.x, bv1.y, bv1.z, bv1.w};
#pragma unroll
        for (int i = 0; i < 8; ++i)
#pragma unroll
          for (int j = 0; j < 8; ++j) acc[i][j] = fmaf(av[i], bv[j], acc[i][j]);
      }
    }
  }
  __syncthreads();  // Es visible (covers step==0 path)

  // ---- fused LSTM pointwise epilogue ----
  const int r_base = r0 + (ty << 3);
#pragma unroll
  for (int ii = 0; ii < 8; ++ii) {
    const int r = r_base + ii;
    const int a = (step > 0) ? act[r] : 0;
    const float* Er = Es + a * 128 + (tx << 3);
#pragma unroll
    for (int jj = 0; jj < 2; ++jj) {
      const int j = j0 + tx * 2 + jj;
      float iv = acc[ii][jj * 4 + 0] + Er[jj * 4 + 0];
      float fv = acc[ii][jj * 4 + 1] + Er[jj * 4 + 1];
      float gv = acc[ii][jj * 4 + 2] + Er[jj * 4 + 2];
      float ov = acc[ii][jj * 4 + 3] + Er[jj * 4 + 3];
      float ig = 1.0f / (1.0f + expf(-iv));
      float fg = 1.0f / (1.0f + expf(-fv));
      float gg = tanhf(gv);
      float og = 1.0f / (1.0f + expf(-ov));
      float cprev = (step > 0) ? c_io[(size_t)r * Hsz + j] : 0.0f;
      float cn = fg * cprev + ig * gg;
      c_io[(size_t)r * Hsz + j] = cn;
      h_out[(size_t)r * Hsz + j] = og * tanhf(cn);
    }
  }
}

// ---------------- decoders + gumbel sampling (wave per row) ----------------
template <int K>
__global__ __launch_bounds__(256) void decide_step(
    const float* __restrict__ h, const float* __restrict__ wn,
    const float* __restrict__ bn, const float* __restrict__ wopi,
    const float* __restrict__ bopi, const float* __restrict__ gum,
    float* __restrict__ oan, float* __restrict__ oao,
    float* __restrict__ oln, float* __restrict__ olo,
    float* __restrict__ oen, float* __restrict__ oeo,
    int* __restrict__ act_next) {
  const int lane = threadIdx.x & 63;
  const int r = (blockIdx.x << 2) + (threadIdx.x >> 6);
  const float* hr = h + (size_t)r * Hsz;
  const float4 hv0 = *(const float4*)(hr + (lane << 3));
  const float4 hv1 = *(const float4*)(hr + (lane << 3) + 4);

  float nl[K];
#pragma unroll
  for (int j = 0; j < K; ++j) {
    const float* w = wn + (size_t)j * Hsz;
    float4 w0 = *(const float4*)(w + (lane << 3));
    float4 w1 = *(const float4*)(w + (lane << 3) + 4);
    float v = hv0.x * w0.x + hv0.y * w0.y + hv0.z * w0.z + hv0.w * w0.w +
              hv1.x * w1.x + hv1.y * w1.y + hv1.z * w1.z + hv1.w * w1.w;
#pragma unroll
    for (int off = 32; off > 0; off >>= 1) v += __shfl_xor(v, off, 64);
    nl[j] = 2.5f * tanhf((v + bn[j]) / 5.0f);
  }
  float ol[8];
#pragma unroll
  for (int j = 0; j < 8; ++j) {
    const float* w = wopi + (size_t)j * Hsz;
    float4 w0 = *(const float4*)(w + (lane << 3));
    float4 w1 = *(const float4*)(w + (lane << 3) + 4);
    float v = hv0.x * w0.x + hv0.y * w0.y + hv0.z * w0.z + hv0.w * w0.w +
              hv1.x * w1.x + hv1.y * w1.y + hv1.z * w1.z + hv1.w * w1.w;
#pragma unroll
    for (int off = 32; off > 0; off >>= 1) v += __shfl_xor(v, off, 64);
    ol[j] = (v + bopi[j]) / 5.0f;
  }

  // node decision
  {
    const float* g = gum + (size_t)r * 8;
    float m = nl[0];
#pragma unroll
    for (int j = 1; j < K; ++j) m = fmaxf(m, nl[j]);
    float se = 0.0f;
#pragma unroll
    for (int j = 0; j < K; ++j) se += expf(nl[j] - m);
    float lse = logf(se);
    int a = 0;
    float best = nl[0] + g[0];
#pragma unroll
    for (int j = 1; j < K; ++j) {
      float v = nl[j] + g[j];
      if (v > best) { best = v; a = j; }
    }
    float ent = 0.0f, sel = 0.0f;
#pragma unroll
    for (int j = 0; j < K; ++j) {
      float lp = nl[j] - m - lse;
      ent -= lp * expf(lp);
      if (j == a) sel = lp;
    }
    if (lane == 0) { oan[r] = (float)a; oln[r] = sel; oen[r] = ent; }
  }
  // op decision
  {
    const float* g = gum + (size_t)Bsz * 8 + (size_t)r * 8;
    float m = ol[0];
#pragma unroll
    for (int j = 1; j < 8; ++j) m = fmaxf(m, ol[j]);
    float se = 0.0f;
#pragma unroll
    for (int j = 0; j < 8; ++j) se += expf(ol[j] - m);
    float lse = logf(se);
    int a = 0;
    float best = ol[0] + g[0];
#pragma unroll
    for (int j = 1; j < 8; ++j) {
      float v = ol[j] + g[j];
      if (v > best) { best = v; a = j; }
    }
    float ent = 0.0f, sel = 0.0f;
#pragma unroll
    for (int j = 0; j < 8; ++j) {
      float lp = ol[j] - m - lse;
      ent -= lp * expf(lp);
      if (j == a) sel = lp;
    }
    if (lane == 0) {
      oao[r] = (float)a; olo[r] = sel; oeo[r] = ent; act_next[r] = a;
    }
  }
}

// ---------------------------------------------------------------------------
extern "C" void kernel_launch(void* const* d_in, const int* in_sizes, int n_in,
                              void* d_out, int out_size, void* d_ws,
                              size_t ws_size, hipStream_t stream) {
  (void)in_sizes; (void)n_in; (void)out_size; (void)ws_size;
  const float* emb = (const float*)d_in[0];
  const float* w_ih = (const float*)d_in[1];
  const float* w_hh = (const float*)d_in[2];
  const float* b_ih = (const float*)d_in[3];
  const float* b_hh = (const float*)d_in[4];
  const float* wn[4] = {(const float*)d_in[5], (const float*)d_in[7],
                        (const float*)d_in[9], (const float*)d_in[11]};
  const float* bn[4] = {(const float*)d_in[6], (const float*)d_in[8],
                        (const float*)d_in[10], (const float*)d_in[12]};
  const float* wop = (const float*)d_in[13];
  const float* bop = (const float*)d_in[14];
  const float* gum = (const float*)d_in[15];

  char* ws = (char*)d_ws;
  const size_t HB = (size_t)Bsz * Hsz * sizeof(float);  // 8 MB
  float* E = (float*)ws;                      // 72 KB
  float* h0 = (float*)(ws + (1 << 17));
  float* h1 = (float*)(ws + (1 << 17) + HB);
  float* c = (float*)(ws + (1 << 17) + 2 * HB);
  int* act = (int*)(ws + (1 << 17) + 3 * HB);

  float* out = (float*)d_out;
  const size_t SZ = (size_t)16 * Bsz;

  precompute_E<<<(9 * G4H) / 256, 256, 0, stream>>>(emb, w_ih, b_ih, b_hh, E);

  float* hb[2] = {h0, h1};
  for (int s = 0; s < 8; ++s) {
    float* hin = hb[s & 1];
    float* hout = hb[(s & 1) ^ 1];
    lstm_gemm<<<512, 256, 0, stream>>>(hin, c, E, act, w_hh, hout, s);

    const int i = s >> 1;
    float* oan = out + (size_t)(2 * s) * Bsz;
    float* oao = out + (size_t)(2 * s + 1) * Bsz;
    float* oln = out + SZ + (size_t)(2 * s) * Bsz;
    float* olo = out + SZ + (size_t)(2 * s + 1) * Bsz;
    float* oen = out + 2 * SZ + (size_t)(2 * s) * Bsz;
    float* oeo = out + 2 * SZ + (size_t)(2 * s + 1) * Bsz;
    const float* gn = gum + (size_t)(2 * s) * Bsz * 8;
    const float* wopi = wop + (size_t)i * 8 * Hsz;
    const float* bopi = bop + (size_t)i * 8;
    switch (i) {
      case 0:
        decide_step<2><<<Bsz / 4, 256, 0, stream>>>(
            hout, wn[0], bn[0], wopi, bopi, gn, oan, oao, oln, olo, oen, oeo, act);
        break;
      case 1:
        decide_step<3><<<Bsz / 4, 256, 0, stream>>>(
            hout, wn[1], bn[1], wopi, bopi, gn, oan, oao, oln, olo, oen, oeo, act);
        break;
      case 2:
        decide_step<4><<<Bsz / 4, 256, 0, stream>>>(
            hout, wn[2], bn[2], wopi, bopi, gn, oan, oao, oln, olo, oen, oeo, act);
        break;
      default:
        decide_step<5><<<Bsz / 4, 256, 0, stream>>>(
            hout, wn[3], bn[3], wopi, bopi, gn, oan, oao, oln, olo, oen, oeo, act);
        break;
    }
  }
}

// Round 2
// 617.514 us; speedup vs baseline: 1.6597x; 1.6597x over previous
//
#include <hip/hip_runtime.h>

// ---------------------------------------------------------------------------
// NASNet controller: 8 sequential LSTM steps (B=4096, H=512) + 16 decisions.
// R2 key insight: rows only differ through sampled op tokens, so h_{s+1} has
// at most 8^s distinct values. Steps 1-4 run on class representatives
// (1/8/64/512 rows) instead of 4096 rows; only steps 5-7 need full GEMMs.
//  - E = emb @ w_ih^T + b_ih + b_hh precomputed once ([9,2048]).
//  - class id chain: cls = cls*8 + op_action, maintained inside decide.
// ---------------------------------------------------------------------------

constexpr int Bsz = 4096;
constexpr int Hsz = 512;
constexpr int G4H = 2048;

// ---------------- E = emb @ w_ih^T + b_ih + b_hh ---------------------------
__global__ __launch_bounds__(256) void precompute_E(
    const float* __restrict__ emb, const float* __restrict__ w_ih,
    const float* __restrict__ b_ih, const float* __restrict__ b_hh,
    float* __restrict__ E) {
  int idx = blockIdx.x * 256 + threadIdx.x;  // t*2048 + col
  int t = idx >> 11;
  int col = idx & 2047;
  const float* er = emb + (size_t)t * Hsz;
  const float* wr = w_ih + (size_t)col * Hsz;
  float acc = 0.0f;
  for (int k = 0; k < Hsz; k += 4) {
    float4 e = *(const float4*)(er + k);
    float4 w = *(const float4*)(wr + k);
    acc += e.x * w.x + e.y * w.y + e.z * w.z + e.w * w.w;
  }
  E[idx] = acc + b_ih[col] + b_hh[col];
}

// ---------------- class GEMM: G[q][col] = dot(h[q], w[col]) ----------------
// wave per output; fine for nq <= 64 (L2-resident w_hh re-reads).
__global__ __launch_bounds__(256) void class_gemm(
    const float* __restrict__ h, const float* __restrict__ w,
    float* __restrict__ G, int nq) {
  const int wid = (blockIdx.x << 2) + (threadIdx.x >> 6);
  const int lane = threadIdx.x & 63;
  const int q = wid >> 11;
  const int col = wid & 2047;
  if (q >= nq) return;
  const float* hr = h + (size_t)q * Hsz + (lane << 3);
  const float* wr = w + (size_t)col * Hsz + (lane << 3);
  float4 a0 = *(const float4*)(hr);
  float4 a1 = *(const float4*)(hr + 4);
  float4 b0 = *(const float4*)(wr);
  float4 b1 = *(const float4*)(wr + 4);
  float v = a0.x * b0.x + a0.y * b0.y + a0.z * b0.z + a0.w * b0.w +
            a1.x * b1.x + a1.y * b1.y + a1.z * b1.z + a1.w * b1.w;
#pragma unroll
  for (int off = 32; off > 0; off >>= 1) v += __shfl_xor(v, off, 64);
  if (lane == 0) G[(size_t)q * G4H + col] = v;
}

// ---------------- 64x64-tiled fp32 GEMM (step 4, M=512) --------------------
// G[M x 2048] = A[M x 512] @ w[2048 x 512]^T. Conflict-free LDS tile.
__global__ __launch_bounds__(256) void gemm64(
    const float* __restrict__ A, const float* __restrict__ Bw,
    float* __restrict__ G) {
  constexpr int LDA = 68;
  __shared__ float As[16 * LDA];
  __shared__ float Bs[16 * LDA];
  const int tid = threadIdx.x;
  const int bx = blockIdx.x & 31;   // 32 col tiles
  const int by = blockIdx.x >> 5;   // 8 row tiles (M=512)
  const int r0 = by * 64, c0 = bx * 64;
  const int tx = tid & 15, ty = tid >> 4;
  const int lr = tid >> 2;          // 0..63
  const int lk = (tid & 3) << 2;    // 0,4,8,12
  const float* Ar = A + (size_t)(r0 + lr) * Hsz;
  const float* Br = Bw + (size_t)(c0 + lr) * Hsz;
  float acc[4][4];
#pragma unroll
  for (int i = 0; i < 4; ++i)
#pragma unroll
    for (int j = 0; j < 4; ++j) acc[i][j] = 0.0f;

  for (int k0 = 0; k0 < Hsz; k0 += 16) {
    float4 a = *(const float4*)(Ar + k0 + lk);
    float4 b = *(const float4*)(Br + k0 + lk);
    __syncthreads();
    As[(lk + 0) * LDA + lr] = a.x;
    As[(lk + 1) * LDA + lr] = a.y;
    As[(lk + 2) * LDA + lr] = a.z;
    As[(lk + 3) * LDA + lr] = a.w;
    Bs[(lk + 0) * LDA + lr] = b.x;
    Bs[(lk + 1) * LDA + lr] = b.y;
    Bs[(lk + 2) * LDA + lr] = b.z;
    Bs[(lk + 3) * LDA + lr] = b.w;
    __syncthreads();
#pragma unroll
    for (int kk = 0; kk < 16; ++kk) {
      float4 av = *(const float4*)&As[kk * LDA + (ty << 2)];
      float4 bv = *(const float4*)&Bs[kk * LDA + (tx << 2)];
      float avs[4] = {av.x, av.y, av.z, av.w};
      float bvs[4] = {bv.x, bv.y, bv.z, bv.w};
#pragma unroll
      for (int i = 0; i < 4; ++i)
#pragma unroll
        for (int j = 0; j < 4; ++j) acc[i][j] = fmaf(avs[i], bvs[j], acc[i][j]);
    }
  }
#pragma unroll
  for (int i = 0; i < 4; ++i)
#pragma unroll
    for (int j = 0; j < 4; ++j)
      G[(size_t)(r0 + (ty << 2) + i) * G4H + c0 + (tx << 2) + j] = acc[i][j];
}

// ---------------- class pointwise: h_out[q], c_out[q], q in [0,nq) ---------
// class key q = (prev_class << 3) | token. G row / c_prev row = q>>3.
__global__ __launch_bounds__(256) void step_pw(
    const float* __restrict__ G, const float* __restrict__ E,
    const float* __restrict__ c_prev, float* __restrict__ h_out,
    float* __restrict__ c_out, int nq) {
  int idx = blockIdx.x * 256 + threadIdx.x;
  if (idx >= nq * Hsz) return;
  int q = idx >> 9, j = idx & 511;
  int gq = q >> 3, er = q & 7;
  const float* Eg = E + (size_t)er * G4H;
  float iv = Eg[j], fv = Eg[512 + j], gv = Eg[1024 + j], ov = Eg[1536 + j];
  if (G) {
    const float* Gg = G + (size_t)gq * G4H;
    iv += Gg[j]; fv += Gg[512 + j]; gv += Gg[1024 + j]; ov += Gg[1536 + j];
  }
  float cp = c_prev ? c_prev[(size_t)gq * Hsz + j] : 0.0f;
  float ig = 1.0f / (1.0f + expf(-iv));
  float fg = 1.0f / (1.0f + expf(-fv));
  float gg = tanhf(gv);
  float og = 1.0f / (1.0f + expf(-ov));
  float cn = fg * cp + ig * gg;
  c_out[idx] = cn;
  h_out[idx] = og * tanhf(cn);
}

// ---------------- step-4 expansion: classes (512) -> full rows (4096) ------
__global__ __launch_bounds__(256) void expand_pw(
    const float* __restrict__ G, const float* __restrict__ E,
    const float* __restrict__ c4, const int* __restrict__ cls3,
    const int* __restrict__ act3, float* __restrict__ h_out,
    float* __restrict__ c_out) {
  int idx = blockIdx.x * 256 + threadIdx.x;  // Bsz*Hsz
  int r = idx >> 9, j = idx & 511;
  int q = cls3[r], er = act3[r];
  const float* Eg = E + (size_t)er * G4H;
  const float* Gg = G + (size_t)q * G4H;
  float iv = Gg[j] + Eg[j];
  float fv = Gg[512 + j] + Eg[512 + j];
  float gv = Gg[1024 + j] + Eg[1024 + j];
  float ov = Gg[1536 + j] + Eg[1536 + j];
  float cp = c4[(size_t)q * Hsz + j];
  float ig = 1.0f / (1.0f + expf(-iv));
  float fg = 1.0f / (1.0f + expf(-fv));
  float gg = tanhf(gv);
  float og = 1.0f / (1.0f + expf(-ov));
  float cn = fg * cp + ig * gg;
  c_out[idx] = cn;
  h_out[idx] = og * tanhf(cn);
}

// ---------------- fused gates GEMM + LSTM pointwise (steps 5-7) ------------
__global__ __launch_bounds__(256) void lstm_gemm(
    const float* __restrict__ h_in, float* __restrict__ c_io,
    const float* __restrict__ E, const int* __restrict__ act,
    const float* __restrict__ w_hh, float* __restrict__ h_out) {
  constexpr int LDT = 132;
  __shared__ float As[16 * LDT];
  __shared__ float Bs[16 * LDT];
  __shared__ float Es[9 * 128];

  const int tid = threadIdx.x;
  const int bx = blockIdx.x & 15;
  const int by = blockIdx.x >> 4;
  const int r0 = by * 128;
  const int j0 = bx * 32;
  const int tx = tid & 15;
  const int ty = tid >> 4;

  for (int idx = tid; idx < 9 * 128; idx += 256) {
    int t = idx >> 7;
    int ct = idx & 127;
    Es[idx] = E[(size_t)t * G4H + ((ct & 3) << 9) + j0 + (ct >> 2)];
  }

  float acc[8][8];
#pragma unroll
  for (int i = 0; i < 8; ++i)
#pragma unroll
    for (int j = 0; j < 8; ++j) acc[i][j] = 0.0f;

  {
    const int lr = tid >> 2;
    const int lk = (tid & 3) << 2;
    const int ct0 = lr, ct1 = lr + 64;
    const int wrow0 = ((ct0 & 3) << 9) + j0 + (ct0 >> 2);
    const int wrow1 = ((ct1 & 3) << 9) + j0 + (ct1 >> 2);
    const float* ha = h_in + (size_t)(r0 + lr) * Hsz;
    const float* hb = h_in + (size_t)(r0 + lr + 64) * Hsz;
    const float* wa = w_hh + (size_t)wrow0 * Hsz;
    const float* wb = w_hh + (size_t)wrow1 * Hsz;

    for (int k0 = 0; k0 < Hsz; k0 += 16) {
      float4 a0 = *(const float4*)(ha + k0 + lk);
      float4 a1 = *(const float4*)(hb + k0 + lk);
      float4 b0 = *(const float4*)(wa + k0 + lk);
      float4 b1 = *(const float4*)(wb + k0 + lk);
      __syncthreads();
      As[(lk + 0) * LDT + lr] = a0.x;
      As[(lk + 1) * LDT + lr] = a0.y;
      As[(lk + 2) * LDT + lr] = a0.z;
      As[(lk + 3) * LDT + lr] = a0.w;
      As[(lk + 0) * LDT + lr + 64] = a1.x;
      As[(lk + 1) * LDT + lr + 64] = a1.y;
      As[(lk + 2) * LDT + lr + 64] = a1.z;
      As[(lk + 3) * LDT + lr + 64] = a1.w;
      Bs[(lk + 0) * LDT + lr] = b0.x;
      Bs[(lk + 1) * LDT + lr] = b0.y;
      Bs[(lk + 2) * LDT + lr] = b0.z;
      Bs[(lk + 3) * LDT + lr] = b0.w;
      Bs[(lk + 0) * LDT + lr + 64] = b1.x;
      Bs[(lk + 1) * LDT + lr + 64] = b1.y;
      Bs[(lk + 2) * LDT + lr + 64] = b1.z;
      Bs[(lk + 3) * LDT + lr + 64] = b1.w;
      __syncthreads();
#pragma unroll
      for (int kk = 0; kk < 16; ++kk) {
        const float* Ab = &As[kk * LDT + (ty << 3)];
        const float* Bb = &Bs[kk * LDT + (tx << 3)];
        float4 av0 = *(const float4*)(Ab);
        float4 av1 = *(const float4*)(Ab + 4);
        float4 bv0 = *(const float4*)(Bb);
        float4 bv1 = *(const float4*)(Bb + 4);
        float av[8] = {av0.x, av0.y, av0.z, av0.w, av1.x, av1.y, av1.z, av1.w};
        float bv[8] = {bv0.x, bv0.y, bv0.z, bv0.w, bv1.x, bv1.y, bv1.z, bv1.w};
#pragma unroll
        for (int i = 0; i < 8; ++i)
#pragma unroll
          for (int j = 0; j < 8; ++j) acc[i][j] = fmaf(av[i], bv[j], acc[i][j]);
      }
    }
  }

  const int r_base = r0 + (ty << 3);
#pragma unroll
  for (int ii = 0; ii < 8; ++ii) {
    const int r = r_base + ii;
    const int a = act[r];
    const float* Er = Es + a * 128 + (tx << 3);
#pragma unroll
    for (int jj = 0; jj < 2; ++jj) {
      const int j = j0 + tx * 2 + jj;
      float iv = acc[ii][jj * 4 + 0] + Er[jj * 4 + 0];
      float fv = acc[ii][jj * 4 + 1] + Er[jj * 4 + 1];
      float gv = acc[ii][jj * 4 + 2] + Er[jj * 4 + 2];
      float ov = acc[ii][jj * 4 + 3] + Er[jj * 4 + 3];
      float ig = 1.0f / (1.0f + expf(-iv));
      float fg = 1.0f / (1.0f + expf(-fv));
      float gg = tanhf(gv);
      float og = 1.0f / (1.0f + expf(-ov));
      float cprev = c_io[(size_t)r * Hsz + j];
      float cn = fg * cprev + ig * gg;
      c_io[(size_t)r * Hsz + j] = cn;
      h_out[(size_t)r * Hsz + j] = og * tanhf(cn);
    }
  }
}

// ---------------- decoders + gumbel sampling (wave per row) ----------------
// hmode: 0 = all rows use h[0]; 1 = per-row h[r]; 2 = h[hidx[r]] (class gather)
template <int K>
__global__ __launch_bounds__(256) void decide_step(
    const float* __restrict__ h, const float* __restrict__ wn,
    const float* __restrict__ bn, const float* __restrict__ wopi,
    const float* __restrict__ bopi, const float* __restrict__ gum,
    float* __restrict__ oan, float* __restrict__ oao,
    float* __restrict__ oln, float* __restrict__ olo,
    float* __restrict__ oen, float* __restrict__ oeo,
    int* __restrict__ act_next, const int* __restrict__ hidx, int hmode,
    const int* __restrict__ cls_prev, int* __restrict__ cls_out) {
  const int lane = threadIdx.x & 63;
  const int r = (blockIdx.x << 2) + (threadIdx.x >> 6);
  const int idx = (hmode == 0) ? 0 : (hmode == 1 ? r : hidx[r]);
  const float* hr = h + (size_t)idx * Hsz;
  const float4 hv0 = *(const float4*)(hr + (lane << 3));
  const float4 hv1 = *(const float4*)(hr + (lane << 3) + 4);

  float nl[K];
#pragma unroll
  for (int j = 0; j < K; ++j) {
    const float* w = wn + (size_t)j * Hsz;
    float4 w0 = *(const float4*)(w + (lane << 3));
    float4 w1 = *(const float4*)(w + (lane << 3) + 4);
    float v = hv0.x * w0.x + hv0.y * w0.y + hv0.z * w0.z + hv0.w * w0.w +
              hv1.x * w1.x + hv1.y * w1.y + hv1.z * w1.z + hv1.w * w1.w;
#pragma unroll
    for (int off = 32; off > 0; off >>= 1) v += __shfl_xor(v, off, 64);
    nl[j] = 2.5f * tanhf((v + bn[j]) / 5.0f);
  }
  float ol[8];
#pragma unroll
  for (int j = 0; j < 8; ++j) {
    const float* w = wopi + (size_t)j * Hsz;
    float4 w0 = *(const float4*)(w + (lane << 3));
    float4 w1 = *(const float4*)(w + (lane << 3) + 4);
    float v = hv0.x * w0.x + hv0.y * w0.y + hv0.z * w0.z + hv0.w * w0.w +
              hv1.x * w1.x + hv1.y * w1.y + hv1.z * w1.z + hv1.w * w1.w;
#pragma unroll
    for (int off = 32; off > 0; off >>= 1) v += __shfl_xor(v, off, 64);
    ol[j] = (v + bopi[j]) / 5.0f;
  }

  // node decision
  {
    const float* g = gum + (size_t)r * 8;
    float m = nl[0];
#pragma unroll
    for (int j = 1; j < K; ++j) m = fmaxf(m, nl[j]);
    float se = 0.0f;
#pragma unroll
    for (int j = 0; j < K; ++j) se += expf(nl[j] - m);
    float lse = logf(se);
    int a = 0;
    float best = nl[0] + g[0];
#pragma unroll
    for (int j = 1; j < K; ++j) {
      float v = nl[j] + g[j];
      if (v > best) { best = v; a = j; }
    }
    float ent = 0.0f, sel = 0.0f;
#pragma unroll
    for (int j = 0; j < K; ++j) {
      float lp = nl[j] - m - lse;
      ent -= lp * expf(lp);
      if (j == a) sel = lp;
    }
    if (lane == 0) { oan[r] = (float)a; oln[r] = sel; oen[r] = ent; }
  }
  // op decision
  {
    const float* g = gum + (size_t)Bsz * 8 + (size_t)r * 8;
    float m = ol[0];
#pragma unroll
    for (int j = 1; j < 8; ++j) m = fmaxf(m, ol[j]);
    float se = 0.0f;
#pragma unroll
    for (int j = 0; j < 8; ++j) se += expf(ol[j] - m);
    float lse = logf(se);
    int a = 0;
    float best = ol[0] + g[0];
#pragma unroll
    for (int j = 1; j < 8; ++j) {
      float v = ol[j] + g[j];
      if (v > best) { best = v; a = j; }
    }
    float ent = 0.0f, sel = 0.0f;
#pragma unroll
    for (int j = 0; j < 8; ++j) {
      float lp = ol[j] - m - lse;
      ent -= lp * expf(lp);
      if (j == a) sel = lp;
    }
    if (lane == 0) {
      oao[r] = (float)a; olo[r] = sel; oeo[r] = ent;
      act_next[r] = a;
      if (cls_out) cls_out[r] = (cls_prev ? cls_prev[r] * 8 : 0) + a;
    }
  }
}

// ---------------------------------------------------------------------------
extern "C" void kernel_launch(void* const* d_in, const int* in_sizes, int n_in,
                              void* d_out, int out_size, void* d_ws,
                              size_t ws_size, hipStream_t stream) {
  (void)in_sizes; (void)n_in; (void)out_size; (void)ws_size;
  const float* emb = (const float*)d_in[0];
  const float* w_ih = (const float*)d_in[1];
  const float* w_hh = (const float*)d_in[2];
  const float* b_ih = (const float*)d_in[3];
  const float* b_hh = (const float*)d_in[4];
  const float* wn[4] = {(const float*)d_in[5], (const float*)d_in[7],
                        (const float*)d_in[9], (const float*)d_in[11]};
  const float* bn[4] = {(const float*)d_in[6], (const float*)d_in[8],
                        (const float*)d_in[10], (const float*)d_in[12]};
  const float* wop = (const float*)d_in[13];
  const float* bop = (const float*)d_in[14];
  const float* gum = (const float*)d_in[15];

  float* ws = (float*)d_ws;
  float* E = ws;                 ws += 9 * G4H;        // 18432
  float* h1 = ws;                ws += Hsz;
  float* c1 = ws;                ws += Hsz;
  float* h2 = ws;                ws += 8 * Hsz;
  float* c2 = ws;                ws += 8 * Hsz;
  float* h3 = ws;                ws += 64 * Hsz;
  float* c3 = ws;                ws += 64 * Hsz;
  float* h4 = ws;                ws += 512 * Hsz;
  float* c4 = ws;                ws += 512 * Hsz;
  float* G = ws;                 ws += 512 * G4H;      // reused steps 1-4
  float* hA = ws;                ws += (size_t)Bsz * Hsz;
  float* hB = ws;                ws += (size_t)Bsz * Hsz;
  float* cF = ws;                ws += (size_t)Bsz * Hsz;
  int* act = (int*)ws;
  int* cls = act + Bsz;

  float* out = (float*)d_out;
  const size_t SZ = (size_t)16 * Bsz;

  // per-decision output pointers + decide launcher
  auto decide = [&](int s, const float* h, int hmode, const int* hidx,
                    const int* cls_prev, int* cls_out) {
    const int i = s >> 1;
    float* oan = out + (size_t)(2 * s) * Bsz;
    float* oao = out + (size_t)(2 * s + 1) * Bsz;
    float* oln = out + SZ + (size_t)(2 * s) * Bsz;
    float* olo = out + SZ + (size_t)(2 * s + 1) * Bsz;
    float* oen = out + 2 * SZ + (size_t)(2 * s) * Bsz;
    float* oeo = out + 2 * SZ + (size_t)(2 * s + 1) * Bsz;
    const float* gn = gum + (size_t)(2 * s) * Bsz * 8;
    const float* wopi = wop + (size_t)i * 8 * Hsz;
    const float* bopi = bop + (size_t)i * 8;
    switch (i) {
      case 0:
        decide_step<2><<<Bsz / 4, 256, 0, stream>>>(h, wn[0], bn[0], wopi, bopi,
            gn, oan, oao, oln, olo, oen, oeo, act, hidx, hmode, cls_prev, cls_out);
        break;
      case 1:
        decide_step<3><<<Bsz / 4, 256, 0, stream>>>(h, wn[1], bn[1], wopi, bopi,
            gn, oan, oao, oln, olo, oen, oeo, act, hidx, hmode, cls_prev, cls_out);
        break;
      case 2:
        decide_step<4><<<Bsz / 4, 256, 0, stream>>>(h, wn[2], bn[2], wopi, bopi,
            gn, oan, oao, oln, olo, oen, oeo, act, hidx, hmode, cls_prev, cls_out);
        break;
      default:
        decide_step<5><<<Bsz / 4, 256, 0, stream>>>(h, wn[3], bn[3], wopi, bopi,
            gn, oan, oao, oln, olo, oen, oeo, act, hidx, hmode, cls_prev, cls_out);
        break;
    }
  };

  precompute_E<<<(9 * G4H) / 256, 256, 0, stream>>>(emb, w_ih, b_ih, b_hh, E);

  // step 0: gates = E[0] uniform -> 1-class h1,c1
  step_pw<<<2, 256, 0, stream>>>(nullptr, E, nullptr, h1, c1, 1);
  decide(0, h1, /*hmode=*/0, nullptr, nullptr, cls);          // cls = C1 = a0

  // step 1: 1-class GEMM -> 8-class h2,c2
  class_gemm<<<512, 256, 0, stream>>>(h1, w_hh, G, 1);
  step_pw<<<16, 256, 0, stream>>>(G, E, c1, h2, c2, 8);
  decide(1, h2, /*hmode=*/2, cls, cls, cls);                  // cls -> C2

  // step 2: 8-class GEMM -> 64-class h3,c3
  class_gemm<<<4096, 256, 0, stream>>>(h2, w_hh, G, 8);
  step_pw<<<128, 256, 0, stream>>>(G, E, c2, h3, c3, 64);
  decide(2, h3, /*hmode=*/2, cls, cls, cls);                  // cls -> C3

  // step 3: 64-class GEMM -> 512-class h4,c4
  class_gemm<<<32768, 256, 0, stream>>>(h3, w_hh, G, 64);
  step_pw<<<1024, 256, 0, stream>>>(G, E, c3, h4, c4, 512);
  decide(3, h4, /*hmode=*/2, cls, nullptr, nullptr);          // act = a3

  // step 4: 512-class GEMM, expand to full rows
  gemm64<<<256, 256, 0, stream>>>(h4, w_hh, G);
  expand_pw<<<(Bsz * Hsz) / 256, 256, 0, stream>>>(G, E, c4, cls, act, hA, cF);
  decide(4, hA, /*hmode=*/1, nullptr, nullptr, nullptr);

  // steps 5-7: full fused GEMM + pointwise
  float* hin = hA;
  float* hout = hB;
  for (int s = 5; s < 8; ++s) {
    lstm_gemm<<<512, 256, 0, stream>>>(hin, cF, E, act, w_hh, hout);
    decide(s, hout, /*hmode=*/1, nullptr, nullptr, nullptr);
    float* t = hin; hin = hout; hout = t;
  }
}